// Round 10
// baseline (266.476 us; speedup 1.0000x reference)
//
#include <hip/hip_runtime.h>

#define N0 200000
#define N1 50000
#define N2 10000
#define E1 1000000
#define E2 250000
#define CIN 128
#define HD  256

// Layer-1 buckets: 64 dsts each (binning); layer-1 compute blocks: 32 dsts
#define SH1   6
#define PK1   18        // src1 < 2^18
#define NB1   782       // ceil(N1/64) binning buckets
#define CAP1  2048      // mean 1279 + ~21 sigma
#define DPB1  64
#define DPB1H 32        // dsts per layer-1 compute block (bucket half)
#define NB1L  1564      // 2 * NB1 compute blocks
#define EB1H  1440      // half-bucket edges + pad
// Layer-2 buckets: 16 dsts each (binning); layer-2 compute blocks: 8 dsts
#define SH2   4
#define PK2   16        // src2 < 2^16
#define NB2   625       // 10000/16 exact
#define CAP2  640       // mean 400 + 12 sigma
#define DPB2  16
#define DPB2H 8         // dsts per layer-2 compute block (bucket half)
#define NB2L  1250      // 2 * NB2 compute blocks
#define EB2H  704       // <= CAP2 edges in one half + pad 56

#define NBIN1 489       // ceil(E1/2048)
#define NBIN2 123       // ceil(E2/2048)
#define NPREP 768
#define NCVT  25000     // N0*CIN/4 / 256 exactly

typedef __attribute__((ext_vector_type(8))) short short8;
typedef __attribute__((ext_vector_type(4))) float f32x4;
typedef __attribute__((ext_vector_type(2))) float f32x2;

__device__ __forceinline__ unsigned short f2bf(float f) {
    unsigned u = __builtin_bit_cast(unsigned, f);
    u = (u + 0x7fffu + ((u >> 16) & 1u)) >> 16;   // RNE
    return (unsigned short)u;
}
__device__ __forceinline__ float bf2f(unsigned short h) {
    unsigned u = ((unsigned)h) << 16;
    return __builtin_bit_cast(float, u);
}

// ---- fp8 e4m3 (OCP) encode/decode -----------------------------------------
__device__ __forceinline__ unsigned enc_fp8x4(float a, float b, float c, float d) {
#if __has_builtin(__builtin_amdgcn_cvt_pk_fp8_f32)
    int p = 0;
    p = __builtin_amdgcn_cvt_pk_fp8_f32(a, b, p, false);   // bytes 0,1
    p = __builtin_amdgcn_cvt_pk_fp8_f32(c, d, p, true);    // bytes 2,3
    return (unsigned)p;
#else
    float vv[4] = {a, b, c, d};
    unsigned out = 0;
    #pragma unroll
    for (int k = 0; k < 4; k++) {
        float f = fminf(fmaxf(vv[k], -448.f), 448.f);
        unsigned u = __builtin_bit_cast(unsigned, f);
        const unsigned s = (u >> 24) & 0x80u;
        u &= 0x7fffffffu;
        unsigned byte;
        if (u < 0x3C800000u) {                         // below 2^-6: e4m3 subnormal
            const float af = __builtin_bit_cast(float, u);
            byte = s | (unsigned)(int)rintf(af * 512.0f);
        } else {
            const unsigned u2 = u + 0x000FFFFFu + ((u >> 20) & 1u);  // RNE @ bit20
            const unsigned e  = (u2 >> 23) - 120u;
            byte = s | ((e & 0xFu) << 3) | ((u2 >> 20) & 7u);
        }
        out |= byte << (8 * k);
    }
    return out;
#endif
}

__device__ __forceinline__ unsigned char enc_fp8_1(float v) {
#if __has_builtin(__builtin_amdgcn_cvt_pk_fp8_f32)
    const int p = __builtin_amdgcn_cvt_pk_fp8_f32(v, v, 0, false);
    return (unsigned char)(p & 0xFF);
#else
    float f = fminf(fmaxf(v, -448.f), 448.f);
    unsigned u = __builtin_bit_cast(unsigned, f);
    const unsigned s = (u >> 24) & 0x80u;
    u &= 0x7fffffffu;
    unsigned byte;
    if (u < 0x3C800000u) {
        const float af = __builtin_bit_cast(float, u);
        byte = s | (unsigned)(int)rintf(af * 512.0f);
    } else {
        const unsigned u2 = u + 0x000FFFFFu + ((u >> 20) & 1u);
        const unsigned e  = (u2 >> 23) - 120u;
        byte = s | ((e & 0xFu) << 3) | ((u2 >> 20) & 7u);
    }
    return (unsigned char)byte;
#endif
}

__device__ __forceinline__ void acc_fp8x4(unsigned w, float* __restrict__ acc) {
#if __has_builtin(__builtin_amdgcn_cvt_pk_f32_fp8)
    const f32x2 lo = __builtin_amdgcn_cvt_pk_f32_fp8((int)w, false);
    const f32x2 hi = __builtin_amdgcn_cvt_pk_f32_fp8((int)w, true);
    acc[0] += lo[0]; acc[1] += lo[1]; acc[2] += hi[0]; acc[3] += hi[1];
#else
    #pragma unroll
    for (int k = 0; k < 4; k++) {
        const unsigned b8   = (w >> (8 * k)) & 0xFFu;
        const unsigned bits = ((b8 & 0x80u) << 24) | ((b8 & 0x7Fu) << 20);
        // exact for normals AND subnormals: f32 subnormal * 2^120 renormalizes
        acc[k] += __builtin_bit_cast(float, bits) * 0x1p120f;
    }
#endif
}

// ---------------------------------------------------------------------------
// bin body: 2048 edges/block -> 1024-slot LDS bucket hist -> 1 global atomic
// per (bucket,block) -> packed (dstlow<<PACKSH | src) scatter to bucket runs.
// ---------------------------------------------------------------------------
template<int SHIFTB, int PACKSH, int CAP>
__device__ __forceinline__ void bin_body(
    int bb, const int* __restrict__ src, const int* __restrict__ dst,
    int* __restrict__ gcnt, unsigned* __restrict__ binned, int E, int* sh)
{
    int* hcnt  = sh;           // 1024
    int* hbase = sh + 1024;    // 1024
    int* hcur  = sh + 2048;    // 1024
    const int t = threadIdx.x;
    #pragma unroll
    for (int j = 0; j < 4; j++) hcnt[t + j * 256] = 0;
    __syncthreads();

    unsigned pk[8];
    int      bk[8];
    const int e0 = bb * 2048;
    #pragma unroll
    for (int j = 0; j < 8; j++) {
        const int e = e0 + j * 256 + t;
        if (e < E) {
            const int d = dst[e];
            const int s = src[e];
            bk[j] = d >> SHIFTB;
            pk[j] = ((unsigned)(d & ((1 << SHIFTB) - 1)) << PACKSH) | (unsigned)s;
            atomicAdd(&hcnt[bk[j]], 1);
        } else bk[j] = -1;
    }
    __syncthreads();

    #pragma unroll
    for (int j = 0; j < 4; j++) {
        const int i = t + j * 256;
        hbase[i] = atomicAdd(&gcnt[i], hcnt[i]);
        hcur[i]  = 0;
    }
    __syncthreads();

    #pragma unroll
    for (int j = 0; j < 8; j++) {
        if (bk[j] >= 0) {
            const int idx = atomicAdd(&hcur[bk[j]], 1);
            binned[(size_t)bk[j] * CAP + hbase[bk[j]] + idx] = pk[j];
        }
    }
}

// ---------------------------------------------------------------------------
// Mega-kernel A: bin1 | bin2 | weight-swizzle | x convert (bf16 rows<N1 +
// fp8 all rows) | zero sentinels
// ---------------------------------------------------------------------------
__global__ __launch_bounds__(256) void megaA_kernel(
    const float* __restrict__ x, unsigned short* __restrict__ xb,
    unsigned char* __restrict__ xf8, unsigned char* __restrict__ hb8,
    const float* __restrict__ Wl1, const float* __restrict__ Wr1,
    const float* __restrict__ Wl2, const float* __restrict__ Wr2,
    unsigned short* __restrict__ wsw1, unsigned short* __restrict__ wsw2,
    const int* __restrict__ src1, const int* __restrict__ dst1,
    const int* __restrict__ src2, const int* __restrict__ dst2,
    int* __restrict__ gcnt1, int* __restrict__ gcnt2,
    unsigned* __restrict__ binned1, unsigned* __restrict__ binned2)
{
    __shared__ int sh[3072];
    const int b = blockIdx.x;
    const int t = threadIdx.x;

    if (b < NBIN1) {
        bin_body<SH1, PK1, CAP1>(b, src1, dst1, gcnt1, binned1, E1, sh);
    } else if (b < NBIN1 + NBIN2) {
        bin_body<SH2, PK2, CAP2>(b - NBIN1, src2, dst2, gcnt2, binned2, E2, sh);
    } else if (b < NBIN1 + NBIN2 + NPREP) {
        const int pb = b - NBIN1 - NBIN2;
        const float* Wl; const float* Wr; unsigned short* wsw; int K, tid;
        if (pb < 256) { Wl = Wl1; Wr = Wr1; wsw = wsw1; K = CIN; tid = pb * 256 + t; }
        else          { Wl = Wl2; Wr = Wr2; wsw = wsw2; K = HD;  tid = (pb - 256) * 256 + t; }
        const int j  = tid & 7;
        const int L  = (tid >> 3) & 63;
        const int nt = (tid >> 9) & 15;
        const int kt = tid >> 13;
        const int k  = kt * 32 + (L >> 4) * 8 + j;
        const int n  = nt * 16 + (L & 15);
        const float v = (k < K) ? Wl[(size_t)k * HD + n]
                                : Wr[(size_t)(k - K) * HD + n];
        wsw[tid] = f2bf(v);
    } else if (b < NBIN1 + NBIN2 + NPREP + NCVT) {
        const int i = (b - NBIN1 - NBIN2 - NPREP) * 256 + t;   // exact cover
        // x is read exactly once -> non-temporal
        const f32x4 v = __builtin_nontemporal_load(&((const f32x4*)x)[i]);
        // fp8 table (all rows) for the layer-1 gather
        ((unsigned*)xf8)[i] = enc_fp8x4(v.x, v.y, v.z, v.w);
        // bf16 rows only for rows < N1 (x_dst operand of layer-1 GEMM)
        if (i < N1 * (CIN / 4)) {
            ushort4 o;
            o.x = f2bf(v.x); o.y = f2bf(v.y); o.z = f2bf(v.z); o.w = f2bf(v.w);
            ((ushort4*)xb)[i] = o;
        }
    } else {
        // zero the sentinel rows used for list padding
        if (t < 32)  ((unsigned*)(xf8 + (size_t)N0 * CIN))[t] = 0u;  // 128 B
        if (t < 64)  ((unsigned*)(hb8 + (size_t)N1 * HD))[t] = 0u;   // 256 B
    }
}

// ---------------------------------------------------------------------------
// Layer-1 mega: one block per 32-dst HALF-bucket (grid 1564 -> ~32 waves/CU),
// 512 threads.
//  A) CSR of this block's 32 dsts (filter binned run by dstlow half)
//  B) gather-mean from fp8 table: quarter-wave (16 lanes x 8 B = 128 B row),
//     ONE round: 32 rows = 8 waves x 4 quarter-waves, 8-deep batches
//  C) GEMM: wave = (m-tile w&1) x (n-quarter w>>1) -> relu(.. + b1):
//       hb8 (fp8, all N1 rows)  = layer-2 gather table
//       hb  (bf16, rows < N2)   = layer-2 GEMM x_dst operand
// ---------------------------------------------------------------------------
__global__ __launch_bounds__(512) void layer1_mega(
    const unsigned short* __restrict__ xb, const unsigned char* __restrict__ xf8,
    const unsigned* __restrict__ binned1, const int* __restrict__ gcnt1,
    const unsigned short* __restrict__ wsw1, const float* __restrict__ bias,
    unsigned short* __restrict__ hb, unsigned char* __restrict__ hb8)
{
    __shared__ int ebuf[EB1H];
    __shared__ int lhist[DPB1H], loff[DPB1H], lcur[DPB1H];
    __shared__ __align__(16) unsigned short aggT[4 * DPB1H * 4 * 8];  // 8 KB

    const int t = threadIdx.x;
    const int b = blockIdx.x;
    const int B = b >> 1;            // binning bucket
    const int H = b & 1;             // which 32-dst half
    const int cnt = gcnt1[B];
    const unsigned* bp = binned1 + (size_t)B * CAP1;

    // ---- A: half-bucket CSR in LDS
    if (t < DPB1H) lhist[t] = 0;
    __syncthreads();
    for (int i = t; i < cnt; i += 512) {
        const int r = (int)(bp[i] >> PK1) - H * DPB1H;
        if ((unsigned)r < (unsigned)DPB1H) atomicAdd(&lhist[r], 1);
    }
    __syncthreads();
    if (t < DPB1H) {                     // single-wave shfl prefix scan
        const int p8 = (lhist[t] + 7) & ~7;
        int sum = p8;
        #pragma unroll
        for (int ofs = 1; ofs < DPB1H; ofs <<= 1) {
            const int u = __shfl_up(sum, ofs);
            if (t >= ofs) sum += u;
        }
        const int st = sum - p8;
        loff[t] = st; lcur[t] = st;
    }
    __syncthreads();
    for (int i = t; i < cnt; i += 512) {
        const unsigned p = bp[i];
        const int r = (int)(p >> PK1) - H * DPB1H;
        if ((unsigned)r < (unsigned)DPB1H) {
            const int slot = atomicAdd(&lcur[r], 1);
            ebuf[slot] = (int)(p & ((1u << PK1) - 1u));
        }
    }
    __syncthreads();
    if (t < DPB1H) {                     // pad each list to x8 with sentinel
        const int h = lhist[t];
        const int np = (h + 7) & ~7;
        const int s0 = loff[t];
        for (int i = s0 + h; i < s0 + np; i++) ebuf[i] = N0;
    }
    __syncthreads();

    // ---- B: gather. quarter-wave per row, single round (32 rows)
    const int w = t >> 6, L = t & 63;
    const int qd = L >> 4, l16 = L & 15;
    const unsigned char* xp8 = xf8 + (size_t)l16 * 8;
    {
        const int r = w * 4 + qd;
        const int base = loff[r];
        const int n    = lhist[r];
        const int npad = (n + 7) & ~7;
        float acc[8];
        #pragma unroll
        for (int j = 0; j < 8; j++) acc[j] = 0.f;
        for (int i = 0; i < npad; i += 8) {
            uint2 v[8];
            #pragma unroll
            for (int u = 0; u < 8; u++) {
                const int s = ebuf[base + i + u];
                v[u] = *(const uint2*)(xp8 + (size_t)s * CIN);
            }
            #pragma unroll
            for (int u = 0; u < 8; u++) {
                acc_fp8x4(v[u].x, acc);
                acc_fp8x4(v[u].y, acc + 4);
            }
        }
        const float sc = 1.0f / fmaxf((float)n, 1.0f);
        short8 o;
        #pragma unroll
        for (int j = 0; j < 8; j++) o[j] = (short)f2bf(acc[j] * sc);
        const int kt = l16 >> 2, q = l16 & 3;     // col = kt*32 + q*8 + j
        *(short8*)&aggT[((kt * DPB1H + r) * 4 + q) * 8] = o;
    }
    __syncthreads();

    // ---- C: GEMM. wave w: m-tile (w&1), n-quarter (w>>1)
    const int m = L & 15, q = L >> 4;
    const int mt = w & 1, nq = w >> 1;
    const int row_l = mt * 16 + m;
    const int rg2 = min(b * DPB1H + row_l, N1 - 1);
    const unsigned short* a2p = xb + (size_t)rg2 * CIN + q * 8;

    f32x4 acc[4];
    #pragma unroll
    for (int nt = 0; nt < 4; nt++) acc[nt] = (f32x4){0.f, 0.f, 0.f, 0.f};

    #pragma unroll
    for (int kt = 0; kt < 8; kt++) {
        short8 af;
        if (kt < 4) af = *(const short8*)&aggT[((kt * DPB1H + row_l) * 4 + q) * 8];
        else        af = *(const short8*)(a2p + (kt - 4) * 32);
        #pragma unroll
        for (int nt = 0; nt < 4; nt++) {
            const int ntg = nq * 4 + nt;
            const short8 bf = *(const short8*)(
                wsw1 + (((size_t)kt * 16 + ntg) * 64 + L) * 8);
            acc[nt] = __builtin_amdgcn_mfma_f32_16x16x32_bf16(af, bf, acc[nt], 0, 0, 0);
        }
    }

    const int orow0 = b * DPB1H + mt * 16 + q * 4;
    #pragma unroll
    for (int nt = 0; nt < 4; nt++) {
        const int col = (nq * 4 + nt) * 16 + m;
        const float bv = bias[col];
        #pragma unroll
        for (int r = 0; r < 4; r++) {
            const int row = orow0 + r;
            if (row < N1) {
                const float v = fmaxf(acc[nt][r] + bv, 0.0f);
                hb8[(size_t)row * HD + col] = enc_fp8_1(v);
                if (row < N2) hb[(size_t)row * HD + col] = f2bf(v);
            }
        }
    }
}

// ---------------------------------------------------------------------------
// Layer-2 mega: one block per 8-dst HALF-bucket (grid 1250 -> ~32 waves/CU),
// 512 threads.
//  A) CSR of this block's 8 dsts (filter binned run by dstlow half)
//  B) gather-mean from hb8 fp8 table: FULL wave per row (64 lanes x 4 B =
//     256 B row), 8 rows = 8 waves, 8-deep batches (sentinel row N1)
//  C) GEMM with 16-row MFMA where A-rows 8..15 duplicate rows 0..7; lanes
//     with q >= 2 (output rows >= 8) skip the store. fp32 out + bias.
// ---------------------------------------------------------------------------
__global__ __launch_bounds__(512) void layer2_mega(
    const unsigned short* __restrict__ hb, const unsigned char* __restrict__ hb8,
    const unsigned* __restrict__ binned2, const int* __restrict__ gcnt2,
    const unsigned short* __restrict__ wsw2, const float* __restrict__ bias,
    float* __restrict__ outp)
{
    __shared__ int ebuf[EB2H];
    __shared__ int lhist[DPB2H], loff[DPB2H], lcur[DPB2H];
    __shared__ __align__(16) unsigned short aggT[8 * DPB2H * 4 * 8];   // 4 KB

    const int t = threadIdx.x;
    const int b = blockIdx.x;
    const int B = b >> 1;            // binning bucket
    const int H = b & 1;             // which 8-dst half
    const int cnt = gcnt2[B];
    const unsigned* bp = binned2 + (size_t)B * CAP2;

    // ---- A: half-bucket CSR in LDS
    if (t < DPB2H) lhist[t] = 0;
    __syncthreads();
    for (int i = t; i < cnt; i += 512) {
        const int r = (int)(bp[i] >> PK2) - H * DPB2H;
        if ((unsigned)r < (unsigned)DPB2H) atomicAdd(&lhist[r], 1);
    }
    __syncthreads();
    if (t < DPB2H) {                     // lanes 0-7 of wave 0: shfl scan
        const int p8 = (lhist[t] + 7) & ~7;
        int sum = p8;
        #pragma unroll
        for (int ofs = 1; ofs < DPB2H; ofs <<= 1) {
            const int u = __shfl_up(sum, ofs);
            if (t >= ofs) sum += u;
        }
        const int st = sum - p8;
        loff[t] = st; lcur[t] = st;
    }
    __syncthreads();
    for (int i = t; i < cnt; i += 512) {
        const unsigned p = bp[i];
        const int r = (int)(p >> PK2) - H * DPB2H;
        if ((unsigned)r < (unsigned)DPB2H) {
            const int slot = atomicAdd(&lcur[r], 1);
            ebuf[slot] = (int)(p & 0xFFFFu);
        }
    }
    __syncthreads();
    if (t < DPB2H) {                     // pad each list to x8 with sentinel
        const int h = lhist[t];
        const int np = (h + 7) & ~7;
        const int s0 = loff[t];
        for (int i = s0 + h; i < s0 + np; i++) ebuf[i] = N1;
    }
    __syncthreads();

    // ---- B: full wave per row (fp8, 256 B = 4 B/lane), 8 rows = 8 waves
    const int w = t >> 6, L = t & 63;
    {
        const int r = w;
        const int base = loff[r];
        const int n    = lhist[r];
        const int npad = (n + 7) & ~7;
        float acc[4];
        #pragma unroll
        for (int j = 0; j < 4; j++) acc[j] = 0.f;
        const unsigned char* hp8 = hb8 + (size_t)L * 4;
        for (int i = 0; i < npad; i += 8) {
            unsigned v[8];
            #pragma unroll
            for (int u = 0; u < 8; u++) {
                const int s = ebuf[base + i + u];
                v[u] = *(const unsigned*)(hp8 + (size_t)s * HD);
            }
            #pragma unroll
            for (int u = 0; u < 8; u++) acc_fp8x4(v[u], acc);
        }
        const float sc = 1.0f / fmaxf((float)n, 1.0f);
        ushort4 o;
        o.x = f2bf(acc[0] * sc); o.y = f2bf(acc[1] * sc);
        o.z = f2bf(acc[2] * sc); o.w = f2bf(acc[3] * sc);
        // lane L covers cols 4L..4L+3: kt = L>>3, q = (L>>1)&3, jo = (L&1)*4
        const int kt = L >> 3, q = (L >> 1) & 3, jo = (L & 1) * 4;
        *(ushort4*)&aggT[(((kt * DPB2H + r) * 4 + q) * 8) + jo] = o;
    }
    __syncthreads();

    // ---- C: GEMM. A-rows 8..15 duplicate 0..7 (m&7); writes only q<2.
    const int m = L & 15, q = L >> 4;
    const int m8 = m & 7;
    const int rg2 = b * DPB2H + m8;        // < N2 always (1249*8+7 = 9999)
    const unsigned short* a2p = hb + (size_t)rg2 * HD + q * 8;

    f32x4 acc[2];
    acc[0] = (f32x4){0.f, 0.f, 0.f, 0.f};
    acc[1] = (f32x4){0.f, 0.f, 0.f, 0.f};

    #pragma unroll
    for (int kt = 0; kt < 16; kt++) {
        short8 af;
        if (kt < 8) af = *(const short8*)&aggT[((kt * DPB2H + m8) * 4 + q) * 8];
        else        af = *(const short8*)(a2p + (kt - 8) * 32);
        #pragma unroll
        for (int nt = 0; nt < 2; nt++) {
            const short8 bf = *(const short8*)(
                wsw2 + (((size_t)kt * 16 + (w * 2 + nt)) * 64 + L) * 8);
            acc[nt] = __builtin_amdgcn_mfma_f32_16x16x32_bf16(af, bf, acc[nt], 0, 0, 0);
        }
    }

    if (q < 2) {                            // output rows q*4..q*4+3 in 0..7
        const int orow0 = b * DPB2H + q * 4;
        #pragma unroll
        for (int nt = 0; nt < 2; nt++) {
            const int col = (w * 2 + nt) * 16 + m;
            const float bv = bias[col];
            #pragma unroll
            for (int r = 0; r < 4; r++)
                outp[(size_t)(orow0 + r) * HD + col] = acc[nt][r] + bv;
        }
    }
}

extern "C" void kernel_launch(void* const* d_in, const int* in_sizes, int n_in,
                              void* d_out, int out_size, void* d_ws, size_t ws_size,
                              hipStream_t stream)
{
    const float* x    = (const float*)d_in[0];
    const int*   src1 = (const int*)  d_in[1];
    const int*   dst1 = (const int*)  d_in[2];
    const int*   src2 = (const int*)  d_in[3];
    const int*   dst2 = (const int*)  d_in[4];
    const float* Wl1  = (const float*)d_in[5];
    const float* Wr1  = (const float*)d_in[6];
    const float* b1   = (const float*)d_in[7];
    const float* Wl2  = (const float*)d_in[8];
    const float* Wr2  = (const float*)d_in[9];
    const float* b2   = (const float*)d_in[10];
    float* out = (float*)d_out;

    // ---- workspace (~65 MB):
    // xb (N1 rows bf16) | xf8 (N0+2 rows fp8) | hb (N2 rows bf16) |
    // hb8 (N1+1 rows fp8) | wsw1 | wsw2 | gcnt | binned1 | binned2
    unsigned short* xb   = (unsigned short*)d_ws;
    unsigned char*  xf8  = (unsigned char*)(xb + (size_t)N1 * CIN);
    unsigned short* hb   = (unsigned short*)(xf8 + (size_t)(N0 + 2) * CIN);
    unsigned char*  hb8  = (unsigned char*)(hb + (size_t)N2 * HD);
    unsigned short* wsw1 = (unsigned short*)(hb8 + (size_t)(N1 + 1) * HD + 256);
    unsigned short* wsw2 = wsw1 + 2 * CIN * HD;
    int* gcnt1 = (int*)(wsw2 + 2 * HD * HD);        // 1024
    int* gcnt2 = gcnt1 + 1024;                      // 1024
    unsigned* binned1 = (unsigned*)(gcnt2 + 1024);  // NB1*CAP1
    unsigned* binned2 = binned1 + (size_t)NB1 * CAP1;

    hipMemsetAsync(gcnt1, 0, 2048 * sizeof(int), stream);

    megaA_kernel<<<NBIN1 + NBIN2 + NPREP + NCVT + 1, 256, 0, stream>>>(
        x, xb, xf8, hb8, Wl1, Wr1, Wl2, Wr2, wsw1, wsw2,
        src1, dst1, src2, dst2, gcnt1, gcnt2, binned1, binned2);

    layer1_mega<<<NB1L, 512, 0, stream>>>(xb, xf8, binned1, gcnt1, wsw1, b1, hb, hb8);
    layer2_mega<<<NB2L, 512, 0, stream>>>(hb, hb8, binned2, gcnt2, wsw2, b2, out);
}

// Round 11
// 258.944 us; speedup vs baseline: 1.0291x; 1.0291x over previous
//
#include <hip/hip_runtime.h>

#define N0 200000
#define N1 50000
#define N2 10000
#define E1 1000000
#define E2 250000
#define CIN 128
#define HD  256

// Layer-1 buckets: 64 dsts each (binning); layer-1 compute blocks: 32 dsts
#define SH1   6
#define PK1   18        // src1 < 2^18
#define NB1   782       // ceil(N1/64) binning buckets
#define CAP1  2048      // mean 1279 + ~21 sigma
#define DPB1  64
#define DPB1H 32        // dsts per layer-1 compute block (bucket half)
#define NB1L  1564      // 2 * NB1 compute blocks
#define EB1H  1440      // half-bucket edges + pad
// Layer-2 buckets: 16 dsts each
#define SH2   4
#define PK2   16        // src2 < 2^16
#define NB2   625       // 10000/16 exact
#define CAP2  640       // mean 400 + 12 sigma
#define DPB2  16

#define NBIN1 489       // ceil(E1/2048)
#define NBIN2 123       // ceil(E2/2048)
#define NPREP 768
#define NCVT  25000     // N0*CIN/4 / 256 exactly

#define EB2   (CAP2 + 128)

typedef __attribute__((ext_vector_type(8))) short short8;
typedef __attribute__((ext_vector_type(4))) float f32x4;
typedef __attribute__((ext_vector_type(2))) float f32x2;

__device__ __forceinline__ unsigned short f2bf(float f) {
    unsigned u = __builtin_bit_cast(unsigned, f);
    u = (u + 0x7fffu + ((u >> 16) & 1u)) >> 16;   // RNE
    return (unsigned short)u;
}
__device__ __forceinline__ float bf2f(unsigned short h) {
    unsigned u = ((unsigned)h) << 16;
    return __builtin_bit_cast(float, u);
}

// ---- fp8 e4m3 (OCP) encode/decode -----------------------------------------
__device__ __forceinline__ unsigned enc_fp8x4(float a, float b, float c, float d) {
#if __has_builtin(__builtin_amdgcn_cvt_pk_fp8_f32)
    int p = 0;
    p = __builtin_amdgcn_cvt_pk_fp8_f32(a, b, p, false);   // bytes 0,1
    p = __builtin_amdgcn_cvt_pk_fp8_f32(c, d, p, true);    // bytes 2,3
    return (unsigned)p;
#else
    float vv[4] = {a, b, c, d};
    unsigned out = 0;
    #pragma unroll
    for (int k = 0; k < 4; k++) {
        float f = fminf(fmaxf(vv[k], -448.f), 448.f);
        unsigned u = __builtin_bit_cast(unsigned, f);
        const unsigned s = (u >> 24) & 0x80u;
        u &= 0x7fffffffu;
        unsigned byte;
        if (u < 0x3C800000u) {                         // below 2^-6: e4m3 subnormal
            const float af = __builtin_bit_cast(float, u);
            byte = s | (unsigned)(int)rintf(af * 512.0f);
        } else {
            const unsigned u2 = u + 0x000FFFFFu + ((u >> 20) & 1u);  // RNE @ bit20
            const unsigned e  = (u2 >> 23) - 120u;
            byte = s | ((e & 0xFu) << 3) | ((u2 >> 20) & 7u);
        }
        out |= byte << (8 * k);
    }
    return out;
#endif
}

__device__ __forceinline__ unsigned char enc_fp8_1(float v) {
#if __has_builtin(__builtin_amdgcn_cvt_pk_fp8_f32)
    const int p = __builtin_amdgcn_cvt_pk_fp8_f32(v, v, 0, false);
    return (unsigned char)(p & 0xFF);
#else
    float f = fminf(fmaxf(v, -448.f), 448.f);
    unsigned u = __builtin_bit_cast(unsigned, f);
    const unsigned s = (u >> 24) & 0x80u;
    u &= 0x7fffffffu;
    unsigned byte;
    if (u < 0x3C800000u) {
        const float af = __builtin_bit_cast(float, u);
        byte = s | (unsigned)(int)rintf(af * 512.0f);
    } else {
        const unsigned u2 = u + 0x000FFFFFu + ((u >> 20) & 1u);
        const unsigned e  = (u2 >> 23) - 120u;
        byte = s | ((e & 0xFu) << 3) | ((u2 >> 20) & 7u);
    }
    return (unsigned char)byte;
#endif
}

__device__ __forceinline__ void acc_fp8x4(unsigned w, float* __restrict__ acc) {
#if __has_builtin(__builtin_amdgcn_cvt_pk_f32_fp8)
    const f32x2 lo = __builtin_amdgcn_cvt_pk_f32_fp8((int)w, false);
    const f32x2 hi = __builtin_amdgcn_cvt_pk_f32_fp8((int)w, true);
    acc[0] += lo[0]; acc[1] += lo[1]; acc[2] += hi[0]; acc[3] += hi[1];
#else
    #pragma unroll
    for (int k = 0; k < 4; k++) {
        const unsigned b8   = (w >> (8 * k)) & 0xFFu;
        const unsigned bits = ((b8 & 0x80u) << 24) | ((b8 & 0x7Fu) << 20);
        // exact for normals AND subnormals: f32 subnormal * 2^120 renormalizes
        acc[k] += __builtin_bit_cast(float, bits) * 0x1p120f;
    }
#endif
}

// ---------------------------------------------------------------------------
// bin body: 2048 edges/block -> 1024-slot LDS bucket hist -> 1 global atomic
// per (bucket,block) -> packed (dstlow<<PACKSH | src) scatter to bucket runs.
// ---------------------------------------------------------------------------
template<int SHIFTB, int PACKSH, int CAP>
__device__ __forceinline__ void bin_body(
    int bb, const int* __restrict__ src, const int* __restrict__ dst,
    int* __restrict__ gcnt, unsigned* __restrict__ binned, int E, int* sh)
{
    int* hcnt  = sh;           // 1024
    int* hbase = sh + 1024;    // 1024
    int* hcur  = sh + 2048;    // 1024
    const int t = threadIdx.x;
    #pragma unroll
    for (int j = 0; j < 4; j++) hcnt[t + j * 256] = 0;
    __syncthreads();

    unsigned pk[8];
    int      bk[8];
    const int e0 = bb * 2048;
    #pragma unroll
    for (int j = 0; j < 8; j++) {
        const int e = e0 + j * 256 + t;
        if (e < E) {
            const int d = dst[e];
            const int s = src[e];
            bk[j] = d >> SHIFTB;
            pk[j] = ((unsigned)(d & ((1 << SHIFTB) - 1)) << PACKSH) | (unsigned)s;
            atomicAdd(&hcnt[bk[j]], 1);
        } else bk[j] = -1;
    }
    __syncthreads();

    #pragma unroll
    for (int j = 0; j < 4; j++) {
        const int i = t + j * 256;
        hbase[i] = atomicAdd(&gcnt[i], hcnt[i]);
        hcur[i]  = 0;
    }
    __syncthreads();

    #pragma unroll
    for (int j = 0; j < 8; j++) {
        if (bk[j] >= 0) {
            const int idx = atomicAdd(&hcur[bk[j]], 1);
            binned[(size_t)bk[j] * CAP + hbase[bk[j]] + idx] = pk[j];
        }
    }
}

// ---------------------------------------------------------------------------
// Mega-kernel A: bin1 | bin2 | weight-swizzle | x convert (bf16 rows<N1 +
// fp8 all rows) | zero sentinels
// ---------------------------------------------------------------------------
__global__ __launch_bounds__(256) void megaA_kernel(
    const float* __restrict__ x, unsigned short* __restrict__ xb,
    unsigned char* __restrict__ xf8, unsigned char* __restrict__ hb8,
    const float* __restrict__ Wl1, const float* __restrict__ Wr1,
    const float* __restrict__ Wl2, const float* __restrict__ Wr2,
    unsigned short* __restrict__ wsw1, unsigned short* __restrict__ wsw2,
    const int* __restrict__ src1, const int* __restrict__ dst1,
    const int* __restrict__ src2, const int* __restrict__ dst2,
    int* __restrict__ gcnt1, int* __restrict__ gcnt2,
    unsigned* __restrict__ binned1, unsigned* __restrict__ binned2)
{
    __shared__ int sh[3072];
    const int b = blockIdx.x;
    const int t = threadIdx.x;

    if (b < NBIN1) {
        bin_body<SH1, PK1, CAP1>(b, src1, dst1, gcnt1, binned1, E1, sh);
    } else if (b < NBIN1 + NBIN2) {
        bin_body<SH2, PK2, CAP2>(b - NBIN1, src2, dst2, gcnt2, binned2, E2, sh);
    } else if (b < NBIN1 + NBIN2 + NPREP) {
        const int pb = b - NBIN1 - NBIN2;
        const float* Wl; const float* Wr; unsigned short* wsw; int K, tid;
        if (pb < 256) { Wl = Wl1; Wr = Wr1; wsw = wsw1; K = CIN; tid = pb * 256 + t; }
        else          { Wl = Wl2; Wr = Wr2; wsw = wsw2; K = HD;  tid = (pb - 256) * 256 + t; }
        const int j  = tid & 7;
        const int L  = (tid >> 3) & 63;
        const int nt = (tid >> 9) & 15;
        const int kt = tid >> 13;
        const int k  = kt * 32 + (L >> 4) * 8 + j;
        const int n  = nt * 16 + (L & 15);
        const float v = (k < K) ? Wl[(size_t)k * HD + n]
                                : Wr[(size_t)(k - K) * HD + n];
        wsw[tid] = f2bf(v);
    } else if (b < NBIN1 + NBIN2 + NPREP + NCVT) {
        const int i = (b - NBIN1 - NBIN2 - NPREP) * 256 + t;   // exact cover
        // x is read exactly once -> non-temporal
        const f32x4 v = __builtin_nontemporal_load(&((const f32x4*)x)[i]);
        // fp8 table (all rows) for the layer-1 gather
        ((unsigned*)xf8)[i] = enc_fp8x4(v.x, v.y, v.z, v.w);
        // bf16 rows only for rows < N1 (x_dst operand of layer-1 GEMM)
        if (i < N1 * (CIN / 4)) {
            ushort4 o;
            o.x = f2bf(v.x); o.y = f2bf(v.y); o.z = f2bf(v.z); o.w = f2bf(v.w);
            ((ushort4*)xb)[i] = o;
        }
    } else {
        // zero the sentinel rows used for list padding
        if (t < 32)  ((unsigned*)(xf8 + (size_t)N0 * CIN))[t] = 0u;  // 128 B
        if (t < 64)  ((unsigned*)(hb8 + (size_t)N1 * HD))[t] = 0u;   // 256 B
    }
}

// ---------------------------------------------------------------------------
// Layer-1 mega: one block per 32-dst HALF-bucket (grid 1564 -> ~32 waves/CU),
// 512 threads.
//  A) CSR of this block's 32 dsts (filter binned run by dstlow half)
//  B) gather-mean from fp8 table: quarter-wave (16 lanes x 8 B = 128 B row),
//     ONE round: 32 rows = 8 waves x 4 quarter-waves, 8-deep batches
//  C) GEMM: wave = (m-tile w&1) x (n-quarter w>>1) -> relu(.. + b1):
//       hb8 (fp8, all N1 rows)  = layer-2 gather table
//       hb  (bf16, rows < N2)   = layer-2 GEMM x_dst operand
// ---------------------------------------------------------------------------
__global__ __launch_bounds__(512) void layer1_mega(
    const unsigned short* __restrict__ xb, const unsigned char* __restrict__ xf8,
    const unsigned* __restrict__ binned1, const int* __restrict__ gcnt1,
    const unsigned short* __restrict__ wsw1, const float* __restrict__ bias,
    unsigned short* __restrict__ hb, unsigned char* __restrict__ hb8)
{
    __shared__ int ebuf[EB1H];
    __shared__ int lhist[DPB1H], loff[DPB1H], lcur[DPB1H];
    __shared__ __align__(16) unsigned short aggT[4 * DPB1H * 4 * 8];  // 8 KB

    const int t = threadIdx.x;
    const int b = blockIdx.x;
    const int B = b >> 1;            // binning bucket
    const int H = b & 1;             // which 32-dst half
    const int cnt = gcnt1[B];
    const unsigned* bp = binned1 + (size_t)B * CAP1;

    // ---- A: half-bucket CSR in LDS
    if (t < DPB1H) lhist[t] = 0;
    __syncthreads();
    for (int i = t; i < cnt; i += 512) {
        const int r = (int)(bp[i] >> PK1) - H * DPB1H;
        if ((unsigned)r < (unsigned)DPB1H) atomicAdd(&lhist[r], 1);
    }
    __syncthreads();
    if (t < DPB1H) {                     // single-wave shfl prefix scan
        const int p8 = (lhist[t] + 7) & ~7;
        int sum = p8;
        #pragma unroll
        for (int ofs = 1; ofs < DPB1H; ofs <<= 1) {
            const int u = __shfl_up(sum, ofs);
            if (t >= ofs) sum += u;
        }
        const int st = sum - p8;
        loff[t] = st; lcur[t] = st;
    }
    __syncthreads();
    for (int i = t; i < cnt; i += 512) {
        const unsigned p = bp[i];
        const int r = (int)(p >> PK1) - H * DPB1H;
        if ((unsigned)r < (unsigned)DPB1H) {
            const int slot = atomicAdd(&lcur[r], 1);
            ebuf[slot] = (int)(p & ((1u << PK1) - 1u));
        }
    }
    __syncthreads();
    if (t < DPB1H) {                     // pad each list to x8 with sentinel
        const int h = lhist[t];
        const int np = (h + 7) & ~7;
        const int s0 = loff[t];
        for (int i = s0 + h; i < s0 + np; i++) ebuf[i] = N0;
    }
    __syncthreads();

    // ---- B: gather. quarter-wave per row, single round (32 rows)
    const int w = t >> 6, L = t & 63;
    const int qd = L >> 4, l16 = L & 15;
    const unsigned char* xp8 = xf8 + (size_t)l16 * 8;
    {
        const int r = w * 4 + qd;
        const int base = loff[r];
        const int n    = lhist[r];
        const int npad = (n + 7) & ~7;
        float acc[8];
        #pragma unroll
        for (int j = 0; j < 8; j++) acc[j] = 0.f;
        for (int i = 0; i < npad; i += 8) {
            uint2 v[8];
            #pragma unroll
            for (int u = 0; u < 8; u++) {
                const int s = ebuf[base + i + u];
                v[u] = *(const uint2*)(xp8 + (size_t)s * CIN);
            }
            #pragma unroll
            for (int u = 0; u < 8; u++) {
                acc_fp8x4(v[u].x, acc);
                acc_fp8x4(v[u].y, acc + 4);
            }
        }
        const float sc = 1.0f / fmaxf((float)n, 1.0f);
        short8 o;
        #pragma unroll
        for (int j = 0; j < 8; j++) o[j] = (short)f2bf(acc[j] * sc);
        const int kt = l16 >> 2, q = l16 & 3;     // col = kt*32 + q*8 + j
        *(short8*)&aggT[((kt * DPB1H + r) * 4 + q) * 8] = o;
    }
    __syncthreads();

    // ---- C: GEMM. wave w: m-tile (w&1), n-quarter (w>>1)
    const int m = L & 15, q = L >> 4;
    const int mt = w & 1, nq = w >> 1;
    const int row_l = mt * 16 + m;
    const int rg2 = min(b * DPB1H + row_l, N1 - 1);
    const unsigned short* a2p = xb + (size_t)rg2 * CIN + q * 8;

    f32x4 acc[4];
    #pragma unroll
    for (int nt = 0; nt < 4; nt++) acc[nt] = (f32x4){0.f, 0.f, 0.f, 0.f};

    #pragma unroll
    for (int kt = 0; kt < 8; kt++) {
        short8 af;
        if (kt < 4) af = *(const short8*)&aggT[((kt * DPB1H + row_l) * 4 + q) * 8];
        else        af = *(const short8*)(a2p + (kt - 4) * 32);
        #pragma unroll
        for (int nt = 0; nt < 4; nt++) {
            const int ntg = nq * 4 + nt;
            const short8 bf = *(const short8*)(
                wsw1 + (((size_t)kt * 16 + ntg) * 64 + L) * 8);
            acc[nt] = __builtin_amdgcn_mfma_f32_16x16x32_bf16(af, bf, acc[nt], 0, 0, 0);
        }
    }

    const int orow0 = b * DPB1H + mt * 16 + q * 4;
    #pragma unroll
    for (int nt = 0; nt < 4; nt++) {
        const int col = (nq * 4 + nt) * 16 + m;
        const float bv = bias[col];
        #pragma unroll
        for (int r = 0; r < 4; r++) {
            const int row = orow0 + r;
            if (row < N1) {
                const float v = fmaxf(acc[nt][r] + bv, 0.0f);
                hb8[(size_t)row * HD + col] = enc_fp8_1(v);
                if (row < N2) hb[(size_t)row * HD + col] = f2bf(v);
            }
        }
    }
}

// ---------------------------------------------------------------------------
// Layer-2 mega: one block per 16-dst bucket, 512 threads. N2 = 625*16 exact.
//  B) gather-mean from hb8 fp8 table: half-wave (32 lanes x 8 B = 256 B row),
//     2 rows/wave, remainder-free 8-deep batches (sentinel row N1)
//  C) 1 m-tile, 8 waves x 2 n-tiles; A-operand x_dst from bf16 hb;
//     fp32 out + bias, no relu.
// ---------------------------------------------------------------------------
__global__ __launch_bounds__(512) void layer2_mega(
    const unsigned short* __restrict__ hb, const unsigned char* __restrict__ hb8,
    const unsigned* __restrict__ binned2, const int* __restrict__ gcnt2,
    const unsigned short* __restrict__ wsw2, const float* __restrict__ bias,
    float* __restrict__ outp)
{
    __shared__ int ebuf[EB2];
    __shared__ int lhist[DPB2], loff[DPB2], lcur[DPB2];
    __shared__ __align__(16) unsigned short aggT[8 * DPB2 * 4 * 8];   // 8 KB

    const int t = threadIdx.x;
    const int b = blockIdx.x;
    const int cnt = gcnt2[b];
    const unsigned* bp = binned2 + (size_t)b * CAP2;

    if (t < DPB2) lhist[t] = 0;
    __syncthreads();
    for (int i = t; i < cnt; i += 512)
        atomicAdd(&lhist[bp[i] >> PK2], 1);
    __syncthreads();
    if (t < DPB2) {                      // lanes 0-15 of wave 0: shfl scan
        const int p8 = (lhist[t] + 7) & ~7;
        int sum = p8;
        #pragma unroll
        for (int ofs = 1; ofs < DPB2; ofs <<= 1) {
            const int u = __shfl_up(sum, ofs);
            if (t >= ofs) sum += u;
        }
        const int st = sum - p8;
        loff[t] = st; lcur[t] = st;
    }
    __syncthreads();
    for (int i = t; i < cnt; i += 512) {
        const unsigned p = bp[i];
        const int slot = atomicAdd(&lcur[p >> PK2], 1);
        ebuf[slot] = (int)(p & 0xFFFFu);
    }
    __syncthreads();
    if (t < DPB2) {
        const int h = lhist[t];
        const int np = (h + 7) & ~7;
        const int s0 = loff[t];
        for (int i = s0 + h; i < s0 + np; i++) ebuf[i] = N1;
    }
    __syncthreads();

    // ---- B: half-wave per row (fp8, 256 B), 16 rows = 8 waves x 2
    const int w = t >> 6, L = t & 63;
    const int hf = L >> 5, l32 = L & 31;
    {
        const int r = w * 2 + hf;
        const int base = loff[r];
        const int n    = lhist[r];
        const int npad = (n + 7) & ~7;
        float acc[8];
        #pragma unroll
        for (int j = 0; j < 8; j++) acc[j] = 0.f;
        const unsigned char* hp8 = hb8 + (size_t)l32 * 8;
        for (int i = 0; i < npad; i += 8) {
            uint2 v[8];
            #pragma unroll
            for (int u = 0; u < 8; u++) {
                const int s = ebuf[base + i + u];
                v[u] = *(const uint2*)(hp8 + (size_t)s * HD);
            }
            #pragma unroll
            for (int u = 0; u < 8; u++) {
                acc_fp8x4(v[u].x, acc);
                acc_fp8x4(v[u].y, acc + 4);
            }
        }
        const float sc = 1.0f / fmaxf((float)n, 1.0f);
        short8 o;
        #pragma unroll
        for (int j = 0; j < 8; j++) o[j] = (short)f2bf(acc[j] * sc);
        const int kt = l32 >> 2, q = l32 & 3;     // col = kt*32 + q*8 + j
        *(short8*)&aggT[((kt * DPB2 + r) * 4 + q) * 8] = o;
    }
    __syncthreads();

    // C: single m-tile; wave w covers n-tiles 2w, 2w+1
    const int m = L & 15, q = L >> 4;
    const int rg2 = b * DPB2 + m;          // exact, no tail; < N2
    const unsigned short* a2p = hb + (size_t)rg2 * HD + q * 8;

    f32x4 acc[2];
    acc[0] = (f32x4){0.f, 0.f, 0.f, 0.f};
    acc[1] = (f32x4){0.f, 0.f, 0.f, 0.f};

    #pragma unroll
    for (int kt = 0; kt < 16; kt++) {
        short8 af;
        if (kt < 8) af = *(const short8*)&aggT[((kt * DPB2 + m) * 4 + q) * 8];
        else        af = *(const short8*)(a2p + (kt - 8) * 32);
        #pragma unroll
        for (int nt = 0; nt < 2; nt++) {
            const short8 bf = *(const short8*)(
                wsw2 + (((size_t)kt * 16 + (w * 2 + nt)) * 64 + L) * 8);
            acc[nt] = __builtin_amdgcn_mfma_f32_16x16x32_bf16(af, bf, acc[nt], 0, 0, 0);
        }
    }

    const int orow0 = b * DPB2 + q * 4;
    #pragma unroll
    for (int nt = 0; nt < 2; nt++) {
        const int col = (w * 2 + nt) * 16 + m;
        const float bv = bias[col];
        #pragma unroll
        for (int r = 0; r < 4; r++)
            outp[(size_t)(orow0 + r) * HD + col] = acc[nt][r] + bv;
    }
}

extern "C" void kernel_launch(void* const* d_in, const int* in_sizes, int n_in,
                              void* d_out, int out_size, void* d_ws, size_t ws_size,
                              hipStream_t stream)
{
    const float* x    = (const float*)d_in[0];
    const int*   src1 = (const int*)  d_in[1];
    const int*   dst1 = (const int*)  d_in[2];
    const int*   src2 = (const int*)  d_in[3];
    const int*   dst2 = (const int*)  d_in[4];
    const float* Wl1  = (const float*)d_in[5];
    const float* Wr1  = (const float*)d_in[6];
    const float* b1   = (const float*)d_in[7];
    const float* Wl2  = (const float*)d_in[8];
    const float* Wr2  = (const float*)d_in[9];
    const float* b2   = (const float*)d_in[10];
    float* out = (float*)d_out;

    // ---- workspace (~65 MB):
    // xb (N1 rows bf16) | xf8 (N0+2 rows fp8) | hb (N2 rows bf16) |
    // hb8 (N1+1 rows fp8) | wsw1 | wsw2 | gcnt | binned1 | binned2
    unsigned short* xb   = (unsigned short*)d_ws;
    unsigned char*  xf8  = (unsigned char*)(xb + (size_t)N1 * CIN);
    unsigned short* hb   = (unsigned short*)(xf8 + (size_t)(N0 + 2) * CIN);
    unsigned char*  hb8  = (unsigned char*)(hb + (size_t)N2 * HD);
    unsigned short* wsw1 = (unsigned short*)(hb8 + (size_t)(N1 + 1) * HD + 256);
    unsigned short* wsw2 = wsw1 + 2 * CIN * HD;
    int* gcnt1 = (int*)(wsw2 + 2 * HD * HD);        // 1024
    int* gcnt2 = gcnt1 + 1024;                      // 1024
    unsigned* binned1 = (unsigned*)(gcnt2 + 1024);  // NB1*CAP1
    unsigned* binned2 = binned1 + (size_t)NB1 * CAP1;

    hipMemsetAsync(gcnt1, 0, 2048 * sizeof(int), stream);

    megaA_kernel<<<NBIN1 + NBIN2 + NPREP + NCVT + 1, 256, 0, stream>>>(
        x, xb, xf8, hb8, Wl1, Wr1, Wl2, Wr2, wsw1, wsw2,
        src1, dst1, src2, dst2, gcnt1, gcnt2, binned1, binned2);

    layer1_mega<<<NB1L, 512, 0, stream>>>(xb, xf8, binned1, gcnt1, wsw1, b1, hb, hb8);
    layer2_mega<<<NB2, 512, 0, stream>>>(hb, hb8, binned2, gcnt2, wsw2, b2, out);
}